// Round 1
// baseline (189.661 us; speedup 1.0000x reference)
//
#include <hip/hip_runtime.h>

// B=8, Cin=Cout=32, H=W=256, K=5. Adaptive bins: start (k*256)/5 = {0,51,102,153,204},
// all length 52 (bins overlap by 1 row/col).
// Pooling is linear: filt_raw[b,o,k,l] = sum_i W[o,i]*xpool_raw[b,i,k,l] + 2704*bias[o]
// so we pool x (tiny) instead of feat, and the 1x1 conv becomes a pure streaming kernel.

#define CIN 32
#define COUT 32
#define HW 256
#define PLANE (HW * HW)
#define BATCH 8
#define KF 5
#define BIN 52

// ---------------- K0: pool x -> xpool_raw[b][i][25] (raw 52x52 bin sums) ----------------
// Grid 2048 = (b*32+i)*8 + strip ; 256 threads = 256 cols; strip = 32 rows.
// Tiny LDS (5.1 KB) -> full occupancy, pure streaming reads.
__global__ __launch_bounds__(256) void pool_x_kernel(const float* __restrict__ x,
                                                     float* __restrict__ xpool) {
    int blk   = blockIdx.x;
    int s     = blk & 7;           // row strip 0..7
    int plane = blk >> 3;          // b*32+i, 0..255
    int t     = threadIdx.x;
    int gy0   = s * 32;

    const float* xp = x + (size_t)plane * PLANE + (size_t)gy0 * HW + t;
    float acc[KF] = {0.f, 0.f, 0.f, 0.f, 0.f};
#pragma unroll
    for (int r = 0; r < 32; ++r) {
        float v  = xp[(size_t)r * HW];
        int   gy = gy0 + r;
#pragma unroll
        for (int k = 0; k < KF; ++k) {            // row-bin membership (bins overlap by 1)
            const int sk = (k * HW) / KF;
            if (gy >= sk && gy < sk + BIN) acc[k] += v;
        }
    }

    __shared__ float lds[KF][HW + 1];             // +1 pad; tail reads proven conflict-free
#pragma unroll
    for (int k = 0; k < KF; ++k) lds[k][t] = acc[k];
    __syncthreads();

    if (t < KF * KF) {                            // 25 workers: (row-bin kk, col-bin ll)
        int kk = t / KF, ll = t - kk * KF;
        int sl = (ll * HW) / KF;
        float ssum = 0.f;
#pragma unroll 4
        for (int w = 0; w < BIN; ++w) ssum += lds[kk][sl + w];
        atomicAdd(&xpool[plane * 25 + t], ssum);  // 2048*25 atomics total - negligible
    }
}

// ---------------- K1: pure 1x1 conv (channel mix), no LDS / no syncs ----------------
// Grid 1024 = b*128 + rowpair; 256 threads; thread owns 2 adjacent pixels (float2).
__global__ __launch_bounds__(256) void conv_kernel(const float* __restrict__ x,
                                                   const float* __restrict__ Wm,
                                                   const float* __restrict__ bias,
                                                   float* __restrict__ feat) {
    int blk = blockIdx.x;
    int b   = blk >> 7;
    int rp  = blk & 127;
    int t   = threadIdx.x;
    int row = rp * 2 + (t >> 7);
    int c2  = (t & 127) * 2;

    const float* xb = x + (size_t)b * CIN * PLANE + (size_t)row * HW + c2;

    float a0[COUT], a1[COUT];
#pragma unroll
    for (int o = 0; o < COUT; ++o) { float bv = bias[o]; a0[o] = bv; a1[o] = bv; }

#pragma unroll
    for (int i = 0; i < CIN; ++i) {
        float2 xv = *(const float2*)(xb + (size_t)i * PLANE);   // 512B per wave-instr
#pragma unroll
        for (int o = 0; o < COUT; ++o) {
            float w = Wm[o * CIN + i];            // thread-uniform -> scalar load
            a0[o] += w * xv.x;
            a1[o] += w * xv.y;
        }
    }

    float* fb = feat + (size_t)b * COUT * PLANE + (size_t)row * HW + c2;
#pragma unroll
    for (int o = 0; o < COUT; ++o) {
        float2 v; v.x = a0[o]; v.y = a1[o];
        *(float2*)(fb + (size_t)o * PLANE) = v;
    }
}

// ---------------- K2: depthwise 5x5, 32-row x 256-col strips, register sliding window ----
// filt computed in prologue from xpool_raw (linearity of pooling).
#define LROW 264   // LDS row stride (floats); interior col x at [lr*LROW + 4 + x]
__global__ __launch_bounds__(256) void dwconv_kernel(const float* __restrict__ feat,
                                                     const float* __restrict__ xpool,
                                                     const float* __restrict__ Wm,
                                                     const float* __restrict__ bias,
                                                     float* __restrict__ out) {
    int bo    = blockIdx.y;            // 0..255  (b*32+o)
    int b     = bo >> 5;
    int o     = bo & 31;
    int strip = blockIdx.x;            // 0..7
    int gy0   = strip * 32;
    int t     = threadIdx.x;

    __shared__ __align__(16) float s[36 * LROW];
    __shared__ float sfilt[25];

    // filt[k][l] = (sum_i W[o,i]*xpool_raw[b,i,k,l] + 2704*bias[o]) / 2704
    if (t < 25) {
        float acc = bias[o] * 2704.0f;
        const float* xp = xpool + (size_t)b * CIN * 25 + t;
#pragma unroll
        for (int i = 0; i < CIN; ++i) acc += Wm[o * CIN + i] * xp[i * 25];
        sfilt[t] = acc * (1.0f / 2704.0f);
    }
    // zero the 2-col pads (LDS idx 2,3 and 260,261) on each of 36 rows
    if (t < 144) {
        int lr = t >> 2, e = t & 3;
        int ci = (e < 2) ? (2 + e) : (258 + e);
        s[lr * LROW + ci] = 0.f;
    }

    const float* fb = feat + (size_t)bo * PLANE;
#pragma unroll
    for (int j = 0; j < 9; ++j) {          // 36 rows x 64 float4 = 2304 / 256 threads
        int idx = t + 256 * j;
        int lr  = idx >> 6;
        int cx  = (idx & 63) * 4;
        int gy  = gy0 - 2 + lr;
        float4 v = {0.f, 0.f, 0.f, 0.f};
        if ((unsigned)gy < (unsigned)HW) v = *(const float4*)(fb + (size_t)gy * HW + cx);
        *(float4*)(&s[lr * LROW + 4 + cx]) = v;
    }
    __syncthreads();

    float fw[25];
#pragma unroll
    for (int j = 0; j < 25; ++j) fw[j] = sfilt[j];   // LDS broadcast once

    int c = t;   // output column
    float w0[5], w1[5], w2[5], w3[5], w4[5];
#pragma unroll
    for (int j = 0; j < 5; ++j) {
        w0[j] = s[0 * LROW + 2 + c + j];
        w1[j] = s[1 * LROW + 2 + c + j];
        w2[j] = s[2 * LROW + 2 + c + j];
        w3[j] = s[3 * LROW + 2 + c + j];
    }
    float* ob = out + (size_t)bo * PLANE + (size_t)gy0 * HW + c;
#pragma unroll
    for (int r = 0; r < 32; ++r) {
#pragma unroll
        for (int j = 0; j < 5; ++j) w4[j] = s[(r + 4) * LROW + 2 + c + j];
        float acc = 0.f;
#pragma unroll
        for (int j = 0; j < 5; ++j) {
            acc += fw[0 * 5 + j] * w0[j];
            acc += fw[1 * 5 + j] * w1[j];
            acc += fw[2 * 5 + j] * w2[j];
            acc += fw[3 * 5 + j] * w3[j];
            acc += fw[4 * 5 + j] * w4[j];
        }
        ob[(size_t)r * HW] = acc;
#pragma unroll
        for (int j = 0; j < 5; ++j) {      // renamed away under full unroll
            w0[j] = w1[j]; w1[j] = w2[j]; w2[j] = w3[j]; w3[j] = w4[j];
        }
    }
}

extern "C" void kernel_launch(void* const* d_in, const int* in_sizes, int n_in,
                              void* d_out, int out_size, void* d_ws, size_t ws_size,
                              hipStream_t stream) {
    const float* x      = (const float*)d_in[0];
    const float* conv_w = (const float*)d_in[1];
    const float* conv_b = (const float*)d_in[2];
    float* out = (float*)d_out;

    float* feat  = (float*)d_ws;                           // 64 MiB
    float* xpool = feat + (size_t)BATCH * COUT * PLANE;    // 8*32*25 floats (raw x bin sums)

    hipMemsetAsync(xpool, 0, BATCH * CIN * 25 * sizeof(float), stream);
    pool_x_kernel<<<dim3(2048), dim3(256), 0, stream>>>(x, xpool);
    conv_kernel<<<dim3(1024), dim3(256), 0, stream>>>(x, conv_w, conv_b, feat);
    dwconv_kernel<<<dim3(8, BATCH * COUT), dim3(256), 0, stream>>>(feat, xpool, conv_w, conv_b, out);
}